// Round 10
// baseline (381.524 us; speedup 1.0000x reference)
//
#include <hip/hip_runtime.h>
#include <hip/hip_bf16.h>

#define NS 48
#define NV 10
#define NATT 78
#define HID 128
#define WTOT 3364
#define NEDGE 50000
#define NNODE 10000
#define EPAD 50048       // 782 * 64
#define EPSV 1e-5f
#define INV_SQRT3 0.57735026918962576f
#define NORM0 0.13130643285972254f   // 1/sqrt(58)
#define NORM1 0.13130643285972254f

// Fixed-point scales for deterministic integer accumulation
#define FXS  2147483648.0f           // 2^31
#define FXSI (1.0 / 2147483648.0)
#define FXQ  268435456.0f            // 2^28
#define FXQI (1.0 / 268435456.0)

// Repacked Bt2 column layout (tiles of 16 cols; 232 real + 2 pad = 234 tiles):
//  A: tiles   0..143  w1  (u=t/3, v=16*(t%3)+col)
//  B: tiles 144..173  w4
//  C: tiles 174..221  w2  one u per tile, col=v (v<10 valid)
//  D: tiles 222..231  w3  one u per tile, col=v (v<10 valid)
//  pad: 232..233 zero
#define CPAD2 3744
#define NTILE 232
#define NGRP  78          // 78 groups x 3 tiles

using half8 = __attribute__((ext_vector_type(8))) _Float16;
using f32x4 = __attribute__((ext_vector_type(4))) float;

__device__ __forceinline__ unsigned short f2h(float x) {
  union { _Float16 h; unsigned short u; } v;
  v.h = (_Float16)x;
  return v.u;
}

__device__ __forceinline__ void atomFx(unsigned long long* p, float x) {
  long long q = (long long)rintf(x * FXS);
  atomicAdd(p, (unsigned long long)q);
}

// cp (repacked col) -> source col in fc_w2/fc_b2, or -1 for zero-pad
__device__ __forceinline__ int cp_to_src(int cp) {
  if (cp < 2304) return cp;                                         // w1
  if (cp < 2784) return 2884 + (cp - 2304);                         // w4
  if (cp < 3552) { int t = cp - 2784; int u = t >> 4, v = t & 15;
                   return (v < 10) ? (2304 + u * 10 + v) : -1; }    // w2
  if (cp < 3712) { int t = cp - 3552; int u = t >> 4, v = t & 15;
                   return (v < 10) ? (2784 + u * 10 + v) : -1; }    // w3
  return -1;                                                        // pad tiles
}

// ---------------- K0: fc_w2 (128 x 3364) -> Bt2 fp16 [CPAD2][128] ---------------
__global__ __launch_bounds__(256) void k_prep_bt2(const float* __restrict__ w2,
                                                  unsigned short* __restrict__ Bt2) {
  int idx = blockIdx.x * 256 + threadIdx.x;   // CPAD2*128 total
  int cp = idx >> 7, k = idx & 127;
  int c_src = cp_to_src(cp);
  Bt2[idx] = (c_src >= 0) ? f2h(w2[(size_t)k * WTOT + c_src]) : (unsigned short)0;
}

// ---------------- K1: h = relu(edge_attr @ fc_w1 + b1) -> fp16 [EPAD][128] ------
__global__ __launch_bounds__(256) void k_fc1(const float* __restrict__ ea,
                                             const float* __restrict__ w1,
                                             const float* __restrict__ b1,
                                             unsigned short* __restrict__ hbf) {
  __shared__ float sT[128][36];
  int tid = threadIdx.x;
  int e0 = blockIdx.x * 32;
  for (int i = tid; i < 32 * 128; i += 256) {
    int el = i >> 7, k = i & 127;
    int e = e0 + el;
    sT[k][el] = (e < NEDGE) ? ea[(size_t)e * 128 + k] : 0.f;
  }
  __syncthreads();
  int cg = tid & 31;
  int eg = tid >> 5;
  float acc[4][4] = {};
  #pragma unroll 4
  for (int k = 0; k < 128; ++k) {
    float4 a = *(const float4*)&sT[k][eg * 4];
    float4 w = *(const float4*)&w1[k * 128 + cg * 4];
    float av[4] = {a.x, a.y, a.z, a.w};
    float wv[4] = {w.x, w.y, w.z, w.w};
    #pragma unroll
    for (int ii = 0; ii < 4; ++ii)
      #pragma unroll
      for (int jj = 0; jj < 4; ++jj)
        acc[ii][jj] += av[ii] * wv[jj];
  }
  float bb[4];
  #pragma unroll
  for (int jj = 0; jj < 4; ++jj) bb[jj] = b1[cg * 4 + jj];
  #pragma unroll
  for (int ii = 0; ii < 4; ++ii) {
    int e = e0 + eg * 4 + ii;
    bool val = e < NEDGE;
    unsigned short h4[4];
    #pragma unroll
    for (int jj = 0; jj < 4; ++jj) {
      float r = val ? fmaxf(acc[ii][jj] + bb[jj], 0.f) : 0.f;
      h4[jj] = f2h(r);
    }
    uint2 pk;
    pk.x = (unsigned)h4[0] | ((unsigned)h4[1] << 16);
    pk.y = (unsigned)h4[2] | ((unsigned)h4[3] << 16);
    *(uint2*)(hbf + (size_t)e * 128 + cg * 4) = pk;
  }
}

// ---------------- K3: fused GEMM + tensor product -------------------------------
// 4 waves/block, 64 edges/block. 78 phases x 3 tiles; TRIPLE-buffered 12KB
// groups via global_load_lds; ONE fused {vmcnt lgkmcnt(0); s_barrier} per phase.
// Safety: head blob of phase p certifies all waves finished reading
// buf[(p-1)%3] == buf[(p+2)%3], so STAGE3(p+2) may issue right after it.
// vmcnt(3): outstanding = groups {p, p+1} (6 loads); oldest 3 = group p done.
// Last phase: only group p in flight -> vmcnt(0).
__global__ __launch_bounds__(256, 3) void k_tp(const unsigned short* __restrict__ hbf,
                                               const unsigned short* __restrict__ Bt2,
                                               const float* __restrict__ fb2,
                                               const int* __restrict__ eidx,
                                               const float* __restrict__ node_attr,
                                               const float* __restrict__ esh,
                                               unsigned long long* __restrict__ summed,
                                               unsigned* __restrict__ cnt) {
  __shared__ half8    bufB[2304];          // 3 groups x 3 tiles x 4KB = 36,864 B
  __shared__ _Float16 sFT16[48][64];       // 6,144 B (transposed s, broadcast reads)
  __shared__ _Float16 vFL16[64][30];       // 3,840 B
  __shared__ _Float16 b2pH[3712];          // 7,424 B (232 tiles x 16)
  // total LDS = 54,272 B exactly -> 3 blocks/CU

  const int tid  = threadIdx.x;
  const int wid  = tid >> 6;
  const int lane = tid & 63;
  const int col  = lane & 15;
  const int quad = lane >> 4;
  const int e0   = blockIdx.x * 64;
  const int elb  = wid * 16 + quad * 4;

  // own-edge scalars in registers (q0 == p0 since NORM0 == NORM1)
  float p0v[4];
  float sh1n[4][3];
  #pragma unroll
  for (int r = 0; r < 4; ++r) {
    int eg = e0 + elb + r;
    float sh0 = 0.f, x = 0.f, y = 0.f, z = 0.f;
    if (eg < NEDGE) {
      float4 s4 = *(const float4*)&esh[(size_t)eg * 4];
      sh0 = s4.x; x = s4.y; y = s4.z; z = s4.w;
    }
    p0v[r] = sh0 * NORM0;
    sh1n[r][0] = x * NORM1; sh1n[r][1] = y * NORM1; sh1n[r][2] = z * NORM1;
  }
  for (int i = tid; i < 3712; i += 256) {
    int c_src = cp_to_src(i);
    b2pH[i] = (c_src >= 0) ? (_Float16)fb2[c_src] : (_Float16)0.f;
  }
  for (int i = tid; i < 64 * NATT; i += 256) {
    int el = i / NATT, a = i % NATT;
    int eg = e0 + el;
    int dst = (eg < NEDGE) ? eidx[NEDGE + eg] : -1;
    float x = (dst >= 0) ? node_attr[(size_t)dst * NATT + a] : 0.f;
    if (a < NS) sFT16[a][el] = (_Float16)x; else vFL16[el][a - NS] = (_Float16)x;
  }
  __syncthreads();

  // A fragments for this wave's 16 edges (full K=128)
  half8 aF0, aF1, aF2, aF3;
  {
    const half8* hp = (const half8*)hbf;
    size_t arow = (size_t)(e0 + wid * 16 + col) * 16;
    aF0 = hp[arow + 0 * 4 + quad];
    aF1 = hp[arow + 1 * 4 + quad];
    aF2 = hp[arow + 2 * 4 + quad];
    aF3 = hp[arow + 3 * 4 + quad];
  }

  // Staging: dest linear by tid within 4KB tile; source pre-swizzled so the
  // swizzled ds_read below is conflict-spread (both-sides rule).
  const char* bt2c = (const char*)Bt2;
  const int colS = tid >> 4, k8sS = tid & 15;
  const size_t gOff = (size_t)(colS * 16 + (k8sS ^ colS)) * 16;

  #define STAGE3(G) do {                                                           \
    int _t0 = (G) * 3;                                                             \
    char* _db = (char*)bufB + ((G) % 3) * 12288 + wid * 1024;                      \
    _Pragma("unroll")                                                              \
    for (int _t = 0; _t < 3; ++_t)                                                 \
      __builtin_amdgcn_global_load_lds(                                            \
        (const __attribute__((address_space(1))) void*)(bt2c + (size_t)(_t0 + _t) * 4096 + gOff), \
        (__attribute__((address_space(3))) void*)(_db + _t * 4096), 16, 0, 0);     \
  } while (0)

  STAGE3(0); STAGE3(1);

  float acc0[4][3] = {};
  float t1a[4] = {};
  float t3a[4][3] = {};

  // invariant ds_read sub-indices
  const int k0 = (0 * 4 + quad) ^ col;
  const int k1 = (1 * 4 + quad) ^ col;
  const int k2 = (2 * 4 + quad) ^ col;
  const int k3 = (3 * 4 + quad) ^ col;
  const int cb = col * 16;

  #pragma unroll 1
  for (int p = 0; p < NGRP; ++p) {
    // ONE fused wait+barrier per phase. lgkmcnt(0): my previous-phase ds_reads
    // are complete; barrier: everyone's are -> buf[(p+2)%3] is free to overwrite.
    if (p < NGRP - 1) {
      asm volatile("s_waitcnt vmcnt(3) lgkmcnt(0)\n\ts_barrier" ::: "memory");
    } else {
      asm volatile("s_waitcnt vmcnt(0) lgkmcnt(0)\n\ts_barrier" ::: "memory");
    }

    const int bb = (p % 3) * 768 + cb;
    half8 b00 = bufB[bb +   0 + k0], b01 = bufB[bb +   0 + k1],
          b02 = bufB[bb +   0 + k2], b03 = bufB[bb +   0 + k3];
    half8 b10 = bufB[bb + 256 + k0], b11 = bufB[bb + 256 + k1],
          b12 = bufB[bb + 256 + k2], b13 = bufB[bb + 256 + k3];
    half8 b20 = bufB[bb + 512 + k0], b21 = bufB[bb + 512 + k1],
          b22 = bufB[bb + 512 + k2], b23 = bufB[bb + 512 + k3];

    if (p < NGRP - 2) STAGE3(p + 2);

    __builtin_amdgcn_s_setprio(1);
    f32x4 m0 = {0.f, 0.f, 0.f, 0.f};
    f32x4 m1 = {0.f, 0.f, 0.f, 0.f};
    f32x4 m2 = {0.f, 0.f, 0.f, 0.f};
    m0 = __builtin_amdgcn_mfma_f32_16x16x32_f16(aF0, b00, m0, 0, 0, 0);
    m1 = __builtin_amdgcn_mfma_f32_16x16x32_f16(aF0, b10, m1, 0, 0, 0);
    m2 = __builtin_amdgcn_mfma_f32_16x16x32_f16(aF0, b20, m2, 0, 0, 0);
    m0 = __builtin_amdgcn_mfma_f32_16x16x32_f16(aF1, b01, m0, 0, 0, 0);
    m1 = __builtin_amdgcn_mfma_f32_16x16x32_f16(aF1, b11, m1, 0, 0, 0);
    m2 = __builtin_amdgcn_mfma_f32_16x16x32_f16(aF1, b21, m2, 0, 0, 0);
    m0 = __builtin_amdgcn_mfma_f32_16x16x32_f16(aF2, b02, m0, 0, 0, 0);
    m1 = __builtin_amdgcn_mfma_f32_16x16x32_f16(aF2, b12, m1, 0, 0, 0);
    m2 = __builtin_amdgcn_mfma_f32_16x16x32_f16(aF2, b22, m2, 0, 0, 0);
    m0 = __builtin_amdgcn_mfma_f32_16x16x32_f16(aF3, b03, m0, 0, 0, 0);
    m1 = __builtin_amdgcn_mfma_f32_16x16x32_f16(aF3, b13, m1, 0, 0, 0);
    m2 = __builtin_amdgcn_mfma_f32_16x16x32_f16(aF3, b23, m2, 0, 0, 0);
    __builtin_amdgcn_s_setprio(0);

    // ---- epilogue (named scalars / static-indexed regs only) ----
    float b2c0 = (float)b2pH[(p * 3 + 0) * 16 + col];
    float b2c1 = (p * 3 + 1 < NTILE) ? (float)b2pH[(p * 3 + 1) * 16 + col] : 0.f;
    float b2c2 = (p * 3 + 2 < NTILE) ? (float)b2pH[(p * 3 + 2) * 16 + col] : 0.f;
    if (p < 48) {                        // region A (w1), u = p
      #pragma unroll
      for (int r = 0; r < 4; ++r) {
        float sfac = (float)sFT16[p][elb + r] * p0v[r];
        acc0[r][0] += (m0[r] + b2c0) * sfac;
        acc0[r][1] += (m1[r] + b2c1) * sfac;
        acc0[r][2] += (m2[r] + b2c2) * sfac;
      }
    } else if (p < 58) {                 // region B (w4), u = p-48
      int u3 = (p - 48) * 3;
      #pragma unroll
      for (int r = 0; r < 4; ++r) {
        int el = elb + r;
        float dfac = ((float)vFL16[el][u3]     * sh1n[r][0] +
                      (float)vFL16[el][u3 + 1] * sh1n[r][1] +
                      (float)vFL16[el][u3 + 2] * sh1n[r][2]) * INV_SQRT3;
        acc0[r][0] += (m0[r] + b2c0) * dfac;
        acc0[r][1] += (m1[r] + b2c1) * dfac;
        acc0[r][2] += (m2[r] + b2c2) * dfac;
      }
    } else if (p < 74) {                 // region C (w2), u = 3(p-58)+j
      int u0 = (p - 58) * 3;
      #pragma unroll
      for (int r = 0; r < 4; ++r) {
        int el = elb + r;
        t1a[r] += (m0[r] + b2c0) * (float)sFT16[u0][el]
                + (m1[r] + b2c1) * (float)sFT16[u0 + 1][el]
                + (m2[r] + b2c2) * (float)sFT16[u0 + 2][el];
      }
    } else {                             // region D (w3), T = 3p+j, guard pad
      int ub = (p - 74) * 3;
      int T0 = p * 3;
      #pragma unroll
      for (int r = 0; r < 4; ++r) {
        int el = elb + r;
        {
          float w = m0[r] + b2c0;
          t3a[r][0] += w * (float)vFL16[el][(ub + 0) * 3 + 0];
          t3a[r][1] += w * (float)vFL16[el][(ub + 0) * 3 + 1];
          t3a[r][2] += w * (float)vFL16[el][(ub + 0) * 3 + 2];
        }
        if (T0 + 1 < NTILE) {
          float w = m1[r] + b2c1;
          t3a[r][0] += w * (float)vFL16[el][(ub + 1) * 3 + 0];
          t3a[r][1] += w * (float)vFL16[el][(ub + 1) * 3 + 1];
          t3a[r][2] += w * (float)vFL16[el][(ub + 1) * 3 + 2];
        }
        if (T0 + 2 < NTILE) {
          float w = m2[r] + b2c2;
          t3a[r][0] += w * (float)vFL16[el][(ub + 2) * 3 + 0];
          t3a[r][1] += w * (float)vFL16[el][(ub + 2) * 3 + 1];
          t3a[r][2] += w * (float)vFL16[el][(ub + 2) * 3 + 2];
        }
      }
    }
  }
  #undef STAGE3

  // ---- Flush: registers -> global integer atomics (deterministic) ----
  #pragma unroll
  for (int r = 0; r < 4; ++r) {
    int eg = e0 + elb + r;
    if (eg >= NEDGE) continue;
    int src = eidx[eg];
    unsigned long long* dp = &summed[(size_t)src * NATT];
    #pragma unroll
    for (int j = 0; j < 3; ++j)
      atomFx(dp + j * 16 + col, acc0[r][j]);
    if (col < 10) {
      float q0 = p0v[r];                 // q0F == p0F (NORM0 == NORM1)
      #pragma unroll
      for (int i = 0; i < 3; ++i)
        atomFx(dp + NS + col * 3 + i,
               t1a[r] * sh1n[r][i] + t3a[r][i] * q0);
    }
  }
  if (tid < 64) {
    int eg = e0 + tid;
    if (eg < NEDGE) atomicAdd(&cnt[eidx[eg]], 1u);
  }
}

// ---------------- K4: mean over segment + residual, accumulate BN stats ---------
__global__ __launch_bounds__(256) void k_node(const unsigned long long* __restrict__ summed,
                                              const unsigned* __restrict__ cnt,
                                              const float* __restrict__ node_attr,
                                              float* __restrict__ outp,
                                              unsigned long long* __restrict__ stats) {
  __shared__ unsigned long long ls[NS], lq[NS], lv[NV];
  int tid = threadIdx.x;
  if (tid < NS) { ls[tid] = 0ull; lq[tid] = 0ull; }
  if (tid < NV) lv[tid] = 0ull;
  __syncthreads();
  int i = blockIdx.x * 256 + tid;
  if (i < NNODE * NATT) {
    int row = i / NATT, colc = i % NATT;
    long long sv = (long long)summed[i];
    float sum = (float)((double)sv * FXSI);
    float x = sum / fmaxf((float)cnt[row], 1.f) + node_attr[i];
    outp[i] = x;
    if (colc < NS) {
      atomicAdd(&ls[colc], (unsigned long long)(long long)rintf(x * FXS));
      atomicAdd(&lq[colc], (unsigned long long)(long long)rintf(x * x * FXQ));
    } else {
      atomicAdd(&lv[(colc - NS) / 3], (unsigned long long)(long long)rintf(x * x * FXQ));
    }
  }
  __syncthreads();
  if (tid < NS) { atomicAdd(&stats[tid], ls[tid]); atomicAdd(&stats[NS + tid], lq[tid]); }
  if (tid < NV) atomicAdd(&stats[96 + tid], lv[tid]);
}

// ---------------- K5: batch norm apply ------------------------------------------
__global__ __launch_bounds__(256) void k_bn(const float* __restrict__ outp,
                                            const unsigned long long* __restrict__ stats,
                                            const float* __restrict__ bnw,
                                            const float* __restrict__ bnb,
                                            float* __restrict__ out) {
  int i = blockIdx.x * 256 + threadIdx.x;
  if (i >= NNODE * NATT) return;
  int colc = i % NATT;
  float x = outp[i];
  float r;
  if (colc < NS) {
    float mean = (float)((double)(long long)stats[colc] * (FXSI / NNODE));
    float ex2  = (float)((double)(long long)stats[NS + colc] * (FXQI / NNODE));
    float var  = ex2 - mean * mean;
    r = (x - mean) * rsqrtf(var + EPSV) * bnw[colc] + bnb[colc];
  } else {
    int u = (colc - NS) / 3;
    float vn = (float)((double)(long long)stats[96 + u] * (FXQI / (3.0 * NNODE)));
    r = x * rsqrtf(vn + EPSV) * bnw[NS + u];
  }
  out[i] = r;
}

extern "C" void kernel_launch(void* const* d_in, const int* in_sizes, int n_in,
                              void* d_out, int out_size, void* d_ws, size_t ws_size,
                              hipStream_t stream) {
  const float* node_attr = (const float*)d_in[0];
  const int*   eidx      = (const int*)d_in[1];
  const float* edge_attr = (const float*)d_in[2];
  const float* esh       = (const float*)d_in[3];
  const float* fw1       = (const float*)d_in[4];
  const float* fb1       = (const float*)d_in[5];
  const float* fw2       = (const float*)d_in[6];
  const float* fb2       = (const float*)d_in[7];
  const float* bnw       = (const float*)d_in[8];
  const float* bnb       = (const float*)d_in[9];
  float* out = (float*)d_out;

  char* ws = (char*)d_ws;
  // layout (bytes) -- total 20,050,752:
  //   Bt2    @ 0        : CPAD2*128*2 =    958,464   (dead after k_tp)
  //   hbf    @ 958464   : EPAD*128*2  = 12,812,288   (dead after k_tp)
  //   summed @ 13770752 : N*78*8     =   6,240,000   (i64 Q31)
  //   cnt    @ 20010752 : N*4        =      40,000   (u32)
  //   outp   @ 0        : N*78*4     =   3,120,000   (reuses Bt2+hbf head, after k_tp)
  //   stats  @ 3120000  : 128*8      =       1,024   (inside dead hbf, after k_tp)
  unsigned short*     Bt2    = (unsigned short*)(ws + 0);
  unsigned short*     hbf    = (unsigned short*)(ws + 958464);
  unsigned long long* summed = (unsigned long long*)(ws + 13770752);
  unsigned*           cnt    = (unsigned*)(ws + 20010752);
  float*              outp   = (float*)(ws + 0);
  unsigned long long* stats  = (unsigned long long*)(ws + 3120000);

  hipMemsetAsync(ws + 13770752, 0, 6240000 + 40000, stream);   // summed + cnt

  k_prep_bt2<<<(CPAD2 * 128) / 256, 256, 0, stream>>>(fw2, Bt2);
  k_fc1<<<EPAD / 32, 256, 0, stream>>>(edge_attr, fw1, fb1, hbf);
  k_tp<<<EPAD / 64, 256, 0, stream>>>(hbf, Bt2, fb2, eidx, node_attr, esh, summed, cnt);
  hipMemsetAsync(ws + 3120000, 0, 1024, stream);
  int nelem_blocks = (NNODE * NATT + 255) / 256;
  k_node<<<nelem_blocks, 256, 0, stream>>>(summed, cnt, node_attr, outp, stats);
  k_bn<<<nelem_blocks, 256, 0, stream>>>(outp, stats, bnw, bnb, out);
}

// Round 11
// 318.863 us; speedup vs baseline: 1.1965x; 1.1965x over previous
//
#include <hip/hip_runtime.h>
#include <hip/hip_bf16.h>

#define NS 48
#define NV 10
#define NATT 78
#define HID 128
#define WTOT 3364
#define NEDGE 50000
#define NNODE 10000
#define EPAD 50048       // 782 * 64
#define EPSV 1e-5f
#define INV_SQRT3 0.57735026918962576f
#define NORM0 0.13130643285972254f   // 1/sqrt(58)
#define NORM1 0.13130643285972254f

// Fixed-point scales for deterministic integer accumulation
#define FXS  2147483648.0f           // 2^31
#define FXSI (1.0 / 2147483648.0)
#define FXQ  268435456.0f            // 2^28
#define FXQI (1.0 / 268435456.0)

// Repacked Bt2 column layout (tiles of 16 cols; 232 real + 2 pad = 234 tiles):
//  A: tiles   0..143  w1  (u=t/3, v=16*(t%3)+col)
//  B: tiles 144..173  w4
//  C: tiles 174..221  w2  one u per tile, col=v (v<10 valid)
//  D: tiles 222..231  w3  one u per tile, col=v (v<10 valid)
//  pad: 232..233 zero
#define CPAD2 3744
#define NTILE 232
#define NGRP  78          // 78 groups x 3 tiles

#define NBLK_NODE 256     // k_node grid (grid-stride); also partials rows

using half8 = __attribute__((ext_vector_type(8))) _Float16;
using f32x4 = __attribute__((ext_vector_type(4))) float;

__device__ __forceinline__ unsigned short f2h(float x) {
  union { _Float16 h; unsigned short u; } v;
  v.h = (_Float16)x;
  return v.u;
}

__device__ __forceinline__ void atomFx(unsigned long long* p, float x) {
  long long q = (long long)rintf(x * FXS);
  atomicAdd(p, (unsigned long long)q);
}

// cp (repacked col) -> source col in fc_w2/fc_b2, or -1 for zero-pad
__device__ __forceinline__ int cp_to_src(int cp) {
  if (cp < 2304) return cp;                                         // w1
  if (cp < 2784) return 2884 + (cp - 2304);                         // w4
  if (cp < 3552) { int t = cp - 2784; int u = t >> 4, v = t & 15;
                   return (v < 10) ? (2304 + u * 10 + v) : -1; }    // w2
  if (cp < 3712) { int t = cp - 3552; int u = t >> 4, v = t & 15;
                   return (v < 10) ? (2784 + u * 10 + v) : -1; }    // w3
  return -1;                                                        // pad tiles
}

// ---------------- K0: fc_w2 (128 x 3364) -> Bt2 fp16 [CPAD2][128] ---------------
__global__ __launch_bounds__(256) void k_prep_bt2(const float* __restrict__ w2,
                                                  unsigned short* __restrict__ Bt2) {
  int idx = blockIdx.x * 256 + threadIdx.x;   // CPAD2*128 total
  int cp = idx >> 7, k = idx & 127;
  int c_src = cp_to_src(cp);
  Bt2[idx] = (c_src >= 0) ? f2h(w2[(size_t)k * WTOT + c_src]) : (unsigned short)0;
}

// ---------------- K1: h = relu(edge_attr @ fc_w1 + b1) -> fp16 [EPAD][128] ------
__global__ __launch_bounds__(256) void k_fc1(const float* __restrict__ ea,
                                             const float* __restrict__ w1,
                                             const float* __restrict__ b1,
                                             unsigned short* __restrict__ hbf) {
  __shared__ float sT[128][36];
  int tid = threadIdx.x;
  int e0 = blockIdx.x * 32;
  for (int i = tid; i < 32 * 128; i += 256) {
    int el = i >> 7, k = i & 127;
    int e = e0 + el;
    sT[k][el] = (e < NEDGE) ? ea[(size_t)e * 128 + k] : 0.f;
  }
  __syncthreads();
  int cg = tid & 31;
  int eg = tid >> 5;
  float acc[4][4] = {};
  #pragma unroll 4
  for (int k = 0; k < 128; ++k) {
    float4 a = *(const float4*)&sT[k][eg * 4];
    float4 w = *(const float4*)&w1[k * 128 + cg * 4];
    float av[4] = {a.x, a.y, a.z, a.w};
    float wv[4] = {w.x, w.y, w.z, w.w};
    #pragma unroll
    for (int ii = 0; ii < 4; ++ii)
      #pragma unroll
      for (int jj = 0; jj < 4; ++jj)
        acc[ii][jj] += av[ii] * wv[jj];
  }
  float bb[4];
  #pragma unroll
  for (int jj = 0; jj < 4; ++jj) bb[jj] = b1[cg * 4 + jj];
  #pragma unroll
  for (int ii = 0; ii < 4; ++ii) {
    int e = e0 + eg * 4 + ii;
    bool val = e < NEDGE;
    unsigned short h4[4];
    #pragma unroll
    for (int jj = 0; jj < 4; ++jj) {
      float r = val ? fmaxf(acc[ii][jj] + bb[jj], 0.f) : 0.f;
      h4[jj] = f2h(r);
    }
    uint2 pk;
    pk.x = (unsigned)h4[0] | ((unsigned)h4[1] << 16);
    pk.y = (unsigned)h4[2] | ((unsigned)h4[3] << 16);
    *(uint2*)(hbf + (size_t)e * 128 + cg * 4) = pk;
  }
}

// ---------------- K3: fused GEMM + tensor product (r8 exact) --------------------
// 4 waves/block, 64 edges/block. 78 phases x 3 tiles; double-buffered 12KB
// groups via global_load_lds; drain-all head wait; named scalars only.
__global__ __launch_bounds__(256, 3) void k_tp(const unsigned short* __restrict__ hbf,
                                               const unsigned short* __restrict__ Bt2,
                                               const float* __restrict__ fb2,
                                               const int* __restrict__ eidx,
                                               const float* __restrict__ node_attr,
                                               const float* __restrict__ esh,
                                               unsigned long long* __restrict__ summed,
                                               unsigned* __restrict__ cnt) {
  __shared__ half8    bufB[1536];        // 2 groups x 3 tiles x 4KB = 24576 B
  __shared__ float    sFT[48][64];       // transposed s: 12288 B (broadcast reads)
  __shared__ float    vFL[64][30];       // 7680 B
  __shared__ _Float16 b2pH[CPAD2];       // 7488 B
  __shared__ float    p0FL[64], q0FL[64];
  __shared__ float    sh1nL[64][3];
  __shared__ int      srcL[64], dstL[64];
  // total LDS = 53,824 B -> 3 blocks/CU

  const int tid  = threadIdx.x;
  const int wid  = tid >> 6;
  const int lane = tid & 63;
  const int col  = lane & 15;
  const int quad = lane >> 4;
  const int e0   = blockIdx.x * 64;
  const int elb  = wid * 16 + quad * 4;

  if (tid < 64) {
    int eg = e0 + tid;
    bool val = eg < NEDGE;
    srcL[tid] = val ? eidx[eg] : -1;
    dstL[tid] = val ? eidx[NEDGE + eg] : -1;
    float sh0 = 0.f, s1x = 0.f, s1y = 0.f, s1z = 0.f;
    if (val) {
      float4 s4 = *(const float4*)&esh[(size_t)eg * 4];
      sh0 = s4.x; s1x = s4.y; s1y = s4.z; s1z = s4.w;
    }
    p0FL[tid] = sh0 * NORM0;
    q0FL[tid] = sh0 * NORM1;
    sh1nL[tid][0] = s1x * NORM1; sh1nL[tid][1] = s1y * NORM1; sh1nL[tid][2] = s1z * NORM1;
  }
  for (int i = tid; i < CPAD2; i += 256) {
    int c_src = cp_to_src(i);
    b2pH[i] = (c_src >= 0) ? (_Float16)fb2[c_src] : (_Float16)0.f;
  }
  __syncthreads();
  for (int i = tid; i < 64 * NATT; i += 256) {
    int el = i / NATT, a = i % NATT;
    int dst = dstL[el];
    float x = (dst >= 0) ? node_attr[(size_t)dst * NATT + a] : 0.f;
    if (a < NS) sFT[a][el] = x; else vFL[el][a - NS] = x;
  }
  __syncthreads();

  // A fragments for this wave's 16 edges (full K=128)
  half8 aF0, aF1, aF2, aF3;
  {
    const half8* hp = (const half8*)hbf;
    size_t arow = (size_t)(e0 + wid * 16 + col) * 16;
    aF0 = hp[arow + 0 * 4 + quad];
    aF1 = hp[arow + 1 * 4 + quad];
    aF2 = hp[arow + 2 * 4 + quad];
    aF3 = hp[arow + 3 * 4 + quad];
  }
  float p0v[4];
  #pragma unroll
  for (int r = 0; r < 4; ++r) p0v[r] = p0FL[elb + r];

  // Staging: dest linear by tid within 4KB tile; source pre-swizzled so the
  // swizzled ds_read below is conflict-spread (both-sides rule).
  const char* bt2c = (const char*)Bt2;
  const int colS = tid >> 4, k8sS = tid & 15;
  const size_t gOff = (size_t)(colS * 16 + (k8sS ^ colS)) * 16;

  #define STAGE3(G) do {                                                           \
    int _t0 = (G) * 3;                                                             \
    char* _db = (char*)bufB + ((G) & 1) * 12288 + wid * 1024;                      \
    _Pragma("unroll")                                                              \
    for (int _t = 0; _t < 3; ++_t)                                                 \
      __builtin_amdgcn_global_load_lds(                                            \
        (const __attribute__((address_space(1))) void*)(bt2c + (size_t)(_t0 + _t) * 4096 + gOff), \
        (__attribute__((address_space(3))) void*)(_db + _t * 4096), 16, 0, 0);     \
  } while (0)

  STAGE3(0); STAGE3(1);

  float acc0[4][3] = {};
  float t1a[4] = {};
  float t3a[4][3] = {};

  // invariant ds_read sub-indices
  const int k0 = (0 * 4 + quad) ^ col;
  const int k1 = (1 * 4 + quad) ^ col;
  const int k2 = (2 * 4 + quad) ^ col;
  const int k3 = (3 * 4 + quad) ^ col;
  const int cb = col * 16;

  #pragma unroll 1
  for (int p = 0; p < NGRP; ++p) {
    asm volatile("s_waitcnt vmcnt(0)\n\ts_barrier" ::: "memory");

    const int bb = ((p & 1) << 9) + ((p & 1) << 8) + cb;   // (p&1)*768 + col*16
    half8 b00 = bufB[bb +   0 + k0], b01 = bufB[bb +   0 + k1],
          b02 = bufB[bb +   0 + k2], b03 = bufB[bb +   0 + k3];
    half8 b10 = bufB[bb + 256 + k0], b11 = bufB[bb + 256 + k1],
          b12 = bufB[bb + 256 + k2], b13 = bufB[bb + 256 + k3];
    half8 b20 = bufB[bb + 512 + k0], b21 = bufB[bb + 512 + k1],
          b22 = bufB[bb + 512 + k2], b23 = bufB[bb + 512 + k3];

    __builtin_amdgcn_s_setprio(1);
    f32x4 m0 = {0.f, 0.f, 0.f, 0.f};
    f32x4 m1 = {0.f, 0.f, 0.f, 0.f};
    f32x4 m2 = {0.f, 0.f, 0.f, 0.f};
    m0 = __builtin_amdgcn_mfma_f32_16x16x32_f16(aF0, b00, m0, 0, 0, 0);
    m1 = __builtin_amdgcn_mfma_f32_16x16x32_f16(aF0, b10, m1, 0, 0, 0);
    m2 = __builtin_amdgcn_mfma_f32_16x16x32_f16(aF0, b20, m2, 0, 0, 0);
    m0 = __builtin_amdgcn_mfma_f32_16x16x32_f16(aF1, b01, m0, 0, 0, 0);
    m1 = __builtin_amdgcn_mfma_f32_16x16x32_f16(aF1, b11, m1, 0, 0, 0);
    m2 = __builtin_amdgcn_mfma_f32_16x16x32_f16(aF1, b21, m2, 0, 0, 0);
    m0 = __builtin_amdgcn_mfma_f32_16x16x32_f16(aF2, b02, m0, 0, 0, 0);
    m1 = __builtin_amdgcn_mfma_f32_16x16x32_f16(aF2, b12, m1, 0, 0, 0);
    m2 = __builtin_amdgcn_mfma_f32_16x16x32_f16(aF2, b22, m2, 0, 0, 0);
    m0 = __builtin_amdgcn_mfma_f32_16x16x32_f16(aF3, b03, m0, 0, 0, 0);
    m1 = __builtin_amdgcn_mfma_f32_16x16x32_f16(aF3, b13, m1, 0, 0, 0);
    m2 = __builtin_amdgcn_mfma_f32_16x16x32_f16(aF3, b23, m2, 0, 0, 0);
    __builtin_amdgcn_s_setprio(0);

    // all waves done reading buf[p&1] before it is overwritten below
    asm volatile("s_waitcnt lgkmcnt(0)\n\ts_barrier" ::: "memory");
    if (p < NGRP - 2) STAGE3(p + 2);

    // ---- epilogue (named scalars only) ----
    float b2c0 = (float)b2pH[(p * 3 + 0) * 16 + col];
    float b2c1 = (float)b2pH[(p * 3 + 1) * 16 + col];
    float b2c2 = (float)b2pH[(p * 3 + 2) * 16 + col];
    if (p < 48) {                        // region A (w1), u = p
      #pragma unroll
      for (int r = 0; r < 4; ++r) {
        float sfac = sFT[p][elb + r] * p0v[r];
        acc0[r][0] += (m0[r] + b2c0) * sfac;
        acc0[r][1] += (m1[r] + b2c1) * sfac;
        acc0[r][2] += (m2[r] + b2c2) * sfac;
      }
    } else if (p < 58) {                 // region B (w4), u = p-48
      int u3 = (p - 48) * 3;
      #pragma unroll
      for (int r = 0; r < 4; ++r) {
        int el = elb + r;
        float dfac = (vFL[el][u3]     * sh1nL[el][0] +
                      vFL[el][u3 + 1] * sh1nL[el][1] +
                      vFL[el][u3 + 2] * sh1nL[el][2]) * INV_SQRT3;
        acc0[r][0] += (m0[r] + b2c0) * dfac;
        acc0[r][1] += (m1[r] + b2c1) * dfac;
        acc0[r][2] += (m2[r] + b2c2) * dfac;
      }
    } else if (p < 74) {                 // region C (w2), u = 3(p-58)+j
      int u0 = (p - 58) * 3;
      #pragma unroll
      for (int r = 0; r < 4; ++r) {
        int el = elb + r;
        t1a[r] += (m0[r] + b2c0) * sFT[u0][el]
                + (m1[r] + b2c1) * sFT[u0 + 1][el]
                + (m2[r] + b2c2) * sFT[u0 + 2][el];
      }
    } else {                             // region D (w3), T = 3p+j, guard pad
      int ub = (p - 74) * 3;
      int T0 = p * 3;
      #pragma unroll
      for (int r = 0; r < 4; ++r) {
        int el = elb + r;
        {
          float w = m0[r] + b2c0;
          t3a[r][0] += w * vFL[el][(ub + 0) * 3 + 0];
          t3a[r][1] += w * vFL[el][(ub + 0) * 3 + 1];
          t3a[r][2] += w * vFL[el][(ub + 0) * 3 + 2];
        }
        if (T0 + 1 < NTILE) {
          float w = m1[r] + b2c1;
          t3a[r][0] += w * vFL[el][(ub + 1) * 3 + 0];
          t3a[r][1] += w * vFL[el][(ub + 1) * 3 + 1];
          t3a[r][2] += w * vFL[el][(ub + 1) * 3 + 2];
        }
        if (T0 + 2 < NTILE) {
          float w = m2[r] + b2c2;
          t3a[r][0] += w * vFL[el][(ub + 2) * 3 + 0];
          t3a[r][1] += w * vFL[el][(ub + 2) * 3 + 1];
          t3a[r][2] += w * vFL[el][(ub + 2) * 3 + 2];
        }
      }
    }
  }
  #undef STAGE3

  // ---- Flush: registers -> global integer atomics (deterministic) ----
  #pragma unroll
  for (int r = 0; r < 4; ++r) {
    int el = elb + r;
    int src = srcL[el];
    if (src < 0) continue;
    unsigned long long* dp = &summed[(size_t)src * NATT];
    #pragma unroll
    for (int j = 0; j < 3; ++j)
      atomFx(dp + j * 16 + col, acc0[r][j]);
    if (col < 10) {
      float q0 = q0FL[el];
      #pragma unroll
      for (int i = 0; i < 3; ++i)
        atomFx(dp + NS + col * 3 + i,
               t1a[r] * sh1nL[el][i] + t3a[r][i] * q0);
    }
  }
  if (tid < 64 && srcL[tid] >= 0) atomicAdd(&cnt[srcL[tid]], 1u);
}

// ---------------- K4: mean + residual + BN-stat partials (grid-stride) ----------
// NBLK_NODE blocks; per-block LDS integer reduce, then a plain STORE of the
// block's 128 partials (NO cross-block atomics -- the 3047-block x 106-address
// same-line u64 atomic storm was the suspected hidden ~100+ us).
__global__ __launch_bounds__(256) void k_node(const unsigned long long* __restrict__ summed,
                                              const unsigned* __restrict__ cnt,
                                              const float* __restrict__ node_attr,
                                              float* __restrict__ outp,
                                              unsigned long long* __restrict__ partials) {
  __shared__ unsigned long long ls[NS], lq[NS], lv[NV];
  int tid = threadIdx.x;
  if (tid < NS) { ls[tid] = 0ull; lq[tid] = 0ull; }
  if (tid < NV) lv[tid] = 0ull;
  __syncthreads();
  for (int i = blockIdx.x * 256 + tid; i < NNODE * NATT; i += NBLK_NODE * 256) {
    int row = i / NATT, colc = i % NATT;
    long long sv = (long long)summed[i];
    float sum = (float)((double)sv * FXSI);
    float x = sum / fmaxf((float)cnt[row], 1.f) + node_attr[i];
    outp[i] = x;
    if (colc < NS) {
      atomicAdd(&ls[colc], (unsigned long long)(long long)rintf(x * FXS));
      atomicAdd(&lq[colc], (unsigned long long)(long long)rintf(x * x * FXQ));
    } else {
      atomicAdd(&lv[(colc - NS) / 3], (unsigned long long)(long long)rintf(x * x * FXQ));
    }
  }
  __syncthreads();
  if (tid < 128) {
    unsigned long long v = 0ull;
    if (tid < NS)            v = ls[tid];
    else if (tid < 2 * NS)   v = lq[tid - NS];
    else if (tid < 96 + NV)  v = lv[tid - 96];
    partials[(size_t)blockIdx.x * 128 + tid] = v;
  }
}

// ---------------- K4b: deterministic partial reduction --------------------------
__global__ __launch_bounds__(128) void k_stats(const unsigned long long* __restrict__ partials,
                                               unsigned long long* __restrict__ stats) {
  int c = threadIdx.x;        // 0..127
  unsigned long long s = 0ull;
  for (int b = 0; b < NBLK_NODE; ++b) s += partials[(size_t)b * 128 + c];
  stats[c] = s;
}

// ---------------- K5: batch norm apply ------------------------------------------
__global__ __launch_bounds__(256) void k_bn(const float* __restrict__ outp,
                                            const unsigned long long* __restrict__ stats,
                                            const float* __restrict__ bnw,
                                            const float* __restrict__ bnb,
                                            float* __restrict__ out) {
  int i = blockIdx.x * 256 + threadIdx.x;
  if (i >= NNODE * NATT) return;
  int colc = i % NATT;
  float x = outp[i];
  float r;
  if (colc < NS) {
    float mean = (float)((double)(long long)stats[colc] * (FXSI / NNODE));
    float ex2  = (float)((double)(long long)stats[NS + colc] * (FXQI / NNODE));
    float var  = ex2 - mean * mean;
    r = (x - mean) * rsqrtf(var + EPSV) * bnw[colc] + bnb[colc];
  } else {
    int u = (colc - NS) / 3;
    float vn = (float)((double)(long long)stats[96 + u] * (FXQI / (3.0 * NNODE)));
    r = x * rsqrtf(vn + EPSV) * bnw[NS + u];
  }
  out[i] = r;
}

extern "C" void kernel_launch(void* const* d_in, const int* in_sizes, int n_in,
                              void* d_out, int out_size, void* d_ws, size_t ws_size,
                              hipStream_t stream) {
  const float* node_attr = (const float*)d_in[0];
  const int*   eidx      = (const int*)d_in[1];
  const float* edge_attr = (const float*)d_in[2];
  const float* esh       = (const float*)d_in[3];
  const float* fw1       = (const float*)d_in[4];
  const float* fb1       = (const float*)d_in[5];
  const float* fw2       = (const float*)d_in[6];
  const float* fb2       = (const float*)d_in[7];
  const float* bnw       = (const float*)d_in[8];
  const float* bnb       = (const float*)d_in[9];
  float* out = (float*)d_out;

  char* ws = (char*)d_ws;
  // layout (bytes) -- total 20,050,752:
  //   Bt2      @ 0        : CPAD2*128*2 =    958,464   (dead after k_tp)
  //   hbf      @ 958464   : EPAD*128*2  = 12,812,288   (dead after k_tp)
  //   summed   @ 13770752 : N*78*8     =   6,240,000   (i64 Q31)
  //   cnt      @ 20010752 : N*4        =      40,000   (u32)
  //   outp     @ 0        : N*78*4     =   3,120,000   (reuses dead head, after k_tp)
  //   partials @ 3120000  : 256*128*8  =     262,144   (inside dead region)
  //   stats    @ 3382144  : 128*8      =       1,024   (inside dead region)
  unsigned short*     Bt2      = (unsigned short*)(ws + 0);
  unsigned short*     hbf      = (unsigned short*)(ws + 958464);
  unsigned long long* summed   = (unsigned long long*)(ws + 13770752);
  unsigned*           cnt      = (unsigned*)(ws + 20010752);
  float*              outp     = (float*)(ws + 0);
  unsigned long long* partials = (unsigned long long*)(ws + 3120000);
  unsigned long long* stats    = (unsigned long long*)(ws + 3382144);

  hipMemsetAsync(ws + 13770752, 0, 6240000 + 40000, stream);   // summed + cnt

  k_prep_bt2<<<(CPAD2 * 128) / 256, 256, 0, stream>>>(fw2, Bt2);
  k_fc1<<<EPAD / 32, 256, 0, stream>>>(edge_attr, fw1, fb1, hbf);
  k_tp<<<EPAD / 64, 256, 0, stream>>>(hbf, Bt2, fb2, eidx, node_attr, esh, summed, cnt);
  k_node<<<NBLK_NODE, 256, 0, stream>>>(summed, cnt, node_attr, outp, partials);
  k_stats<<<1, 128, 0, stream>>>(partials, stats);
  int nelem_blocks = (NNODE * NATT + 255) / 256;
  k_bn<<<nelem_blocks, 256, 0, stream>>>(outp, stats, bnw, bnb, out);
}

// Round 12
// 293.792 us; speedup vs baseline: 1.2986x; 1.0853x over previous
//
#include <hip/hip_runtime.h>
#include <hip/hip_bf16.h>

#define NS 48
#define NV 10
#define NATT 78
#define HID 128
#define WTOT 3364
#define NEDGE 50000
#define NNODE 10000
#define EPAD 50048       // 782 * 64
#define EPSV 1e-5f
#define INV_SQRT3 0.57735026918962576f
#define NORM0 0.13130643285972254f   // 1/sqrt(58)
#define NORM1 0.13130643285972254f

// Fixed-point scales for deterministic integer accumulation
#define FXS  2147483648.0f           // 2^31
#define FXSI (1.0 / 2147483648.0)
#define FXQ  268435456.0f            // 2^28
#define FXQI (1.0 / 268435456.0)

// Repacked Bt2 column layout (tiles of 16 cols; 232 real + 2 pad = 234 tiles)
#define CPAD2 3744
#define NTILE 232
#define NGRP  78          // 78 groups x 3 tiles

#define NBLK_NODE 256     // k_node grid; partials rows

// merged front kernel grid segments
#define PREP_BLKS 1872    // CPAD2*128/256
#define FC1_BLKS  782     // EPAD/64
#define ZERO_BYTES 6280000        // summed (6,240,000) + cnt (40,000)
#define ZERO_BLKS 1534            // ZERO_BYTES/16/256 = 1533.2 -> 1534 (guarded)

using half8 = __attribute__((ext_vector_type(8))) _Float16;
using f32x4 = __attribute__((ext_vector_type(4))) float;

__device__ __forceinline__ unsigned short f2h(float x) {
  union { _Float16 h; unsigned short u; } v;
  v.h = (_Float16)x;
  return v.u;
}

__device__ __forceinline__ void atomFx(unsigned long long* p, float x) {
  long long q = (long long)rintf(x * FXS);
  atomicAdd(p, (unsigned long long)q);
}

// cp (repacked col) -> source col in fc_w2/fc_b2, or -1 for zero-pad
__device__ __forceinline__ int cp_to_src(int cp) {
  if (cp < 2304) return cp;                                         // w1
  if (cp < 2784) return 2884 + (cp - 2304);                         // w4
  if (cp < 3552) { int t = cp - 2784; int u = t >> 4, v = t & 15;
                   return (v < 10) ? (2304 + u * 10 + v) : -1; }    // w2
  if (cp < 3712) { int t = cp - 3552; int u = t >> 4, v = t & 15;
                   return (v < 10) ? (2784 + u * 10 + v) : -1; }    // w3
  return -1;                                                        // pad tiles
}

// ---------------- K0: merged {Bt2 prep | fc1 MFMA | workspace zero} -------------
// segment A (bid < PREP_BLKS): fc_w2 -> Bt2 fp16 [CPAD2][128]
// segment B (next FC1_BLKS):   h = relu(ea @ w1 + b1) -> fp16 [EPAD][128], MFMA
// segment C (rest):            zero summed+cnt (replaces hipMemsetAsync launch)
__global__ __launch_bounds__(256) void k_front(const float* __restrict__ w2,
                                               unsigned short* __restrict__ Bt2,
                                               const float* __restrict__ ea,
                                               const float* __restrict__ w1,
                                               const float* __restrict__ b1,
                                               unsigned short* __restrict__ hbf,
                                               char* __restrict__ zbase) {
  __shared__ _Float16 w1T[128][136];   // transposed w1, 16B-aligned rows (34,816 B)
  const int bid = blockIdx.x;
  const int tid = threadIdx.x;

  if (bid < PREP_BLKS) {
    int idx = bid * 256 + tid;         // CPAD2*128 total
    int cp = idx >> 7, k = idx & 127;
    int c_src = cp_to_src(cp);
    Bt2[idx] = (c_src >= 0) ? f2h(w2[(size_t)k * WTOT + c_src]) : (unsigned short)0;
    return;
  }
  if (bid >= PREP_BLKS + FC1_BLKS) {
    size_t off = ((size_t)(bid - PREP_BLKS - FC1_BLKS) * 256 + tid) * 16;
    if (off < ZERO_BYTES) *(uint4*)(zbase + off) = make_uint4(0, 0, 0, 0);
    return;
  }

  // ---- fc1 MFMA segment ----
  const int b  = bid - PREP_BLKS;
  const int e0 = b * 64;
  for (int i = tid; i < 128 * 128; i += 256) {
    int k = i >> 7, n = i & 127;       // coalesced read of w1[k][n]
    w1T[n][k] = (_Float16)w1[i];
  }
  __syncthreads();

  const int lane = tid & 63, wid = tid >> 6;
  const int col = lane & 15, quad = lane >> 4;
  // A fragments: lane holds edge row (e0 + wid*16 + col), k chunk ks*32+quad*8
  int e  = e0 + wid * 16 + col;
  int er = (e < NEDGE) ? e : 0;        // clamp: tail rows discarded downstream
  const float* ear = ea + (size_t)er * 128;
  half8 aF[4];
  #pragma unroll
  for (int ks = 0; ks < 4; ++ks) {
    float4 x0 = *(const float4*)&ear[ks * 32 + quad * 8];
    float4 x1 = *(const float4*)&ear[ks * 32 + quad * 8 + 4];
    half8 a;
    a[0] = (_Float16)x0.x; a[1] = (_Float16)x0.y; a[2] = (_Float16)x0.z; a[3] = (_Float16)x0.w;
    a[4] = (_Float16)x1.x; a[5] = (_Float16)x1.y; a[6] = (_Float16)x1.z; a[7] = (_Float16)x1.w;
    aF[ks] = a;
  }
  const int erow = e0 + wid * 16 + quad * 4;   // D row base (edges)
  #pragma unroll
  for (int t = 0; t < 8; ++t) {
    float b1c = b1[t * 16 + col];
    f32x4 m = {0.f, 0.f, 0.f, 0.f};
    #pragma unroll
    for (int ks = 0; ks < 4; ++ks) {
      half8 bf = *(const half8*)&w1T[t * 16 + col][ks * 32 + quad * 8];
      m = __builtin_amdgcn_mfma_f32_16x16x32_f16(aF[ks], bf, m, 0, 0, 0);
    }
    #pragma unroll
    for (int r = 0; r < 4; ++r) {
      float h = fmaxf(m[r] + b1c, 0.f);
      hbf[(size_t)(erow + r) * 128 + t * 16 + col] = f2h(h);
    }
  }
}

// ---------------- K3: fused GEMM + tensor product (r8 exact) --------------------
__global__ __launch_bounds__(256, 3) void k_tp(const unsigned short* __restrict__ hbf,
                                               const unsigned short* __restrict__ Bt2,
                                               const float* __restrict__ fb2,
                                               const int* __restrict__ eidx,
                                               const float* __restrict__ node_attr,
                                               const float* __restrict__ esh,
                                               unsigned long long* __restrict__ summed,
                                               unsigned* __restrict__ cnt) {
  __shared__ half8    bufB[1536];        // 2 groups x 3 tiles x 4KB = 24576 B
  __shared__ float    sFT[48][64];       // transposed s: 12288 B (broadcast reads)
  __shared__ float    vFL[64][30];       // 7680 B
  __shared__ _Float16 b2pH[CPAD2];       // 7488 B
  __shared__ float    p0FL[64], q0FL[64];
  __shared__ float    sh1nL[64][3];
  __shared__ int      srcL[64], dstL[64];

  const int tid  = threadIdx.x;
  const int wid  = tid >> 6;
  const int lane = tid & 63;
  const int col  = lane & 15;
  const int quad = lane >> 4;
  const int e0   = blockIdx.x * 64;
  const int elb  = wid * 16 + quad * 4;

  if (tid < 64) {
    int eg = e0 + tid;
    bool val = eg < NEDGE;
    srcL[tid] = val ? eidx[eg] : -1;
    dstL[tid] = val ? eidx[NEDGE + eg] : -1;
    float sh0 = 0.f, s1x = 0.f, s1y = 0.f, s1z = 0.f;
    if (val) {
      float4 s4 = *(const float4*)&esh[(size_t)eg * 4];
      sh0 = s4.x; s1x = s4.y; s1y = s4.z; s1z = s4.w;
    }
    p0FL[tid] = sh0 * NORM0;
    q0FL[tid] = sh0 * NORM1;
    sh1nL[tid][0] = s1x * NORM1; sh1nL[tid][1] = s1y * NORM1; sh1nL[tid][2] = s1z * NORM1;
  }
  for (int i = tid; i < CPAD2; i += 256) {
    int c_src = cp_to_src(i);
    b2pH[i] = (c_src >= 0) ? (_Float16)fb2[c_src] : (_Float16)0.f;
  }
  __syncthreads();
  for (int i = tid; i < 64 * NATT; i += 256) {
    int el = i / NATT, a = i % NATT;
    int dst = dstL[el];
    float x = (dst >= 0) ? node_attr[(size_t)dst * NATT + a] : 0.f;
    if (a < NS) sFT[a][el] = x; else vFL[el][a - NS] = x;
  }
  __syncthreads();

  half8 aF0, aF1, aF2, aF3;
  {
    const half8* hp = (const half8*)hbf;
    size_t arow = (size_t)(e0 + wid * 16 + col) * 16;
    aF0 = hp[arow + 0 * 4 + quad];
    aF1 = hp[arow + 1 * 4 + quad];
    aF2 = hp[arow + 2 * 4 + quad];
    aF3 = hp[arow + 3 * 4 + quad];
  }
  float p0v[4];
  #pragma unroll
  for (int r = 0; r < 4; ++r) p0v[r] = p0FL[elb + r];

  const char* bt2c = (const char*)Bt2;
  const int colS = tid >> 4, k8sS = tid & 15;
  const size_t gOff = (size_t)(colS * 16 + (k8sS ^ colS)) * 16;

  #define STAGE3(G) do {                                                           \
    int _t0 = (G) * 3;                                                             \
    char* _db = (char*)bufB + ((G) & 1) * 12288 + wid * 1024;                      \
    _Pragma("unroll")                                                              \
    for (int _t = 0; _t < 3; ++_t)                                                 \
      __builtin_amdgcn_global_load_lds(                                            \
        (const __attribute__((address_space(1))) void*)(bt2c + (size_t)(_t0 + _t) * 4096 + gOff), \
        (__attribute__((address_space(3))) void*)(_db + _t * 4096), 16, 0, 0);     \
  } while (0)

  STAGE3(0); STAGE3(1);

  float acc0[4][3] = {};
  float t1a[4] = {};
  float t3a[4][3] = {};

  const int k0 = (0 * 4 + quad) ^ col;
  const int k1 = (1 * 4 + quad) ^ col;
  const int k2 = (2 * 4 + quad) ^ col;
  const int k3 = (3 * 4 + quad) ^ col;
  const int cb = col * 16;

  #pragma unroll 1
  for (int p = 0; p < NGRP; ++p) {
    asm volatile("s_waitcnt vmcnt(0)\n\ts_barrier" ::: "memory");

    const int bb = ((p & 1) << 9) + ((p & 1) << 8) + cb;
    half8 b00 = bufB[bb +   0 + k0], b01 = bufB[bb +   0 + k1],
          b02 = bufB[bb +   0 + k2], b03 = bufB[bb +   0 + k3];
    half8 b10 = bufB[bb + 256 + k0], b11 = bufB[bb + 256 + k1],
          b12 = bufB[bb + 256 + k2], b13 = bufB[bb + 256 + k3];
    half8 b20 = bufB[bb + 512 + k0], b21 = bufB[bb + 512 + k1],
          b22 = bufB[bb + 512 + k2], b23 = bufB[bb + 512 + k3];

    __builtin_amdgcn_s_setprio(1);
    f32x4 m0 = {0.f, 0.f, 0.f, 0.f};
    f32x4 m1 = {0.f, 0.f, 0.f, 0.f};
    f32x4 m2 = {0.f, 0.f, 0.f, 0.f};
    m0 = __builtin_amdgcn_mfma_f32_16x16x32_f16(aF0, b00, m0, 0, 0, 0);
    m1 = __builtin_amdgcn_mfma_f32_16x16x32_f16(aF0, b10, m1, 0, 0, 0);
    m2 = __builtin_amdgcn_mfma_f32_16x16x32_f16(aF0, b20, m2, 0, 0, 0);
    m0 = __builtin_amdgcn_mfma_f32_16x16x32_f16(aF1, b01, m0, 0, 0, 0);
    m1 = __builtin_amdgcn_mfma_f32_16x16x32_f16(aF1, b11, m1, 0, 0, 0);
    m2 = __builtin_amdgcn_mfma_f32_16x16x32_f16(aF1, b21, m2, 0, 0, 0);
    m0 = __builtin_amdgcn_mfma_f32_16x16x32_f16(aF2, b02, m0, 0, 0, 0);
    m1 = __builtin_amdgcn_mfma_f32_16x16x32_f16(aF2, b12, m1, 0, 0, 0);
    m2 = __builtin_amdgcn_mfma_f32_16x16x32_f16(aF2, b22, m2, 0, 0, 0);
    m0 = __builtin_amdgcn_mfma_f32_16x16x32_f16(aF3, b03, m0, 0, 0, 0);
    m1 = __builtin_amdgcn_mfma_f32_16x16x32_f16(aF3, b13, m1, 0, 0, 0);
    m2 = __builtin_amdgcn_mfma_f32_16x16x32_f16(aF3, b23, m2, 0, 0, 0);
    __builtin_amdgcn_s_setprio(0);

    asm volatile("s_waitcnt lgkmcnt(0)\n\ts_barrier" ::: "memory");
    if (p < NGRP - 2) STAGE3(p + 2);

    float b2c0 = (float)b2pH[(p * 3 + 0) * 16 + col];
    float b2c1 = (float)b2pH[(p * 3 + 1) * 16 + col];
    float b2c2 = (float)b2pH[(p * 3 + 2) * 16 + col];
    if (p < 48) {                        // region A (w1), u = p
      #pragma unroll
      for (int r = 0; r < 4; ++r) {
        float sfac = sFT[p][elb + r] * p0v[r];
        acc0[r][0] += (m0[r] + b2c0) * sfac;
        acc0[r][1] += (m1[r] + b2c1) * sfac;
        acc0[r][2] += (m2[r] + b2c2) * sfac;
      }
    } else if (p < 58) {                 // region B (w4), u = p-48
      int u3 = (p - 48) * 3;
      #pragma unroll
      for (int r = 0; r < 4; ++r) {
        int el = elb + r;
        float dfac = (vFL[el][u3]     * sh1nL[el][0] +
                      vFL[el][u3 + 1] * sh1nL[el][1] +
                      vFL[el][u3 + 2] * sh1nL[el][2]) * INV_SQRT3;
        acc0[r][0] += (m0[r] + b2c0) * dfac;
        acc0[r][1] += (m1[r] + b2c1) * dfac;
        acc0[r][2] += (m2[r] + b2c2) * dfac;
      }
    } else if (p < 74) {                 // region C (w2), u = 3(p-58)+j
      int u0 = (p - 58) * 3;
      #pragma unroll
      for (int r = 0; r < 4; ++r) {
        int el = elb + r;
        t1a[r] += (m0[r] + b2c0) * sFT[u0][el]
                + (m1[r] + b2c1) * sFT[u0 + 1][el]
                + (m2[r] + b2c2) * sFT[u0 + 2][el];
      }
    } else {                             // region D (w3), T = 3p+j, guard pad
      int ub = (p - 74) * 3;
      int T0 = p * 3;
      #pragma unroll
      for (int r = 0; r < 4; ++r) {
        int el = elb + r;
        {
          float w = m0[r] + b2c0;
          t3a[r][0] += w * vFL[el][(ub + 0) * 3 + 0];
          t3a[r][1] += w * vFL[el][(ub + 0) * 3 + 1];
          t3a[r][2] += w * vFL[el][(ub + 0) * 3 + 2];
        }
        if (T0 + 1 < NTILE) {
          float w = m1[r] + b2c1;
          t3a[r][0] += w * vFL[el][(ub + 1) * 3 + 0];
          t3a[r][1] += w * vFL[el][(ub + 1) * 3 + 1];
          t3a[r][2] += w * vFL[el][(ub + 1) * 3 + 2];
        }
        if (T0 + 2 < NTILE) {
          float w = m2[r] + b2c2;
          t3a[r][0] += w * vFL[el][(ub + 2) * 3 + 0];
          t3a[r][1] += w * vFL[el][(ub + 2) * 3 + 1];
          t3a[r][2] += w * vFL[el][(ub + 2) * 3 + 2];
        }
      }
    }
  }
  #undef STAGE3

  #pragma unroll
  for (int r = 0; r < 4; ++r) {
    int el = elb + r;
    int src = srcL[el];
    if (src < 0) continue;
    unsigned long long* dp = &summed[(size_t)src * NATT];
    #pragma unroll
    for (int j = 0; j < 3; ++j)
      atomFx(dp + j * 16 + col, acc0[r][j]);
    if (col < 10) {
      float q0 = q0FL[el];
      #pragma unroll
      for (int i = 0; i < 3; ++i)
        atomFx(dp + NS + col * 3 + i,
               t1a[r] * sh1nL[el][i] + t3a[r][i] * q0);
    }
  }
  if (tid < 64 && srcL[tid] >= 0) atomicAdd(&cnt[srcL[tid]], 1u);
}

// ---------------- K4: mean + residual + BN-stat partials (grid-stride) ----------
__global__ __launch_bounds__(256) void k_node(const unsigned long long* __restrict__ summed,
                                              const unsigned* __restrict__ cnt,
                                              const float* __restrict__ node_attr,
                                              float* __restrict__ outp,
                                              unsigned long long* __restrict__ partials) {
  __shared__ unsigned long long ls[NS], lq[NS], lv[NV];
  int tid = threadIdx.x;
  if (tid < NS) { ls[tid] = 0ull; lq[tid] = 0ull; }
  if (tid < NV) lv[tid] = 0ull;
  __syncthreads();
  for (int i = blockIdx.x * 256 + tid; i < NNODE * NATT; i += NBLK_NODE * 256) {
    int row = i / NATT, colc = i % NATT;
    long long sv = (long long)summed[i];
    float sum = (float)((double)sv * FXSI);
    float x = sum / fmaxf((float)cnt[row], 1.f) + node_attr[i];
    outp[i] = x;
    if (colc < NS) {
      atomicAdd(&ls[colc], (unsigned long long)(long long)rintf(x * FXS));
      atomicAdd(&lq[colc], (unsigned long long)(long long)rintf(x * x * FXQ));
    } else {
      atomicAdd(&lv[(colc - NS) / 3], (unsigned long long)(long long)rintf(x * x * FXQ));
    }
  }
  __syncthreads();
  if (tid < 128) {
    unsigned long long v = 0ull;
    if (tid < NS)            v = ls[tid];
    else if (tid < 2 * NS)   v = lq[tid - NS];
    else if (tid < 96 + NV)  v = lv[tid - 96];
    partials[(size_t)blockIdx.x * 128 + tid] = v;
  }
}

// ---------------- K4b: deterministic partial reduction --------------------------
__global__ __launch_bounds__(128) void k_stats(const unsigned long long* __restrict__ partials,
                                               unsigned long long* __restrict__ stats) {
  int c = threadIdx.x;        // 0..127
  unsigned long long s = 0ull;
  for (int b = 0; b < NBLK_NODE; ++b) s += partials[(size_t)b * 128 + c];
  stats[c] = s;
}

// ---------------- K5: batch norm apply ------------------------------------------
__global__ __launch_bounds__(256) void k_bn(const float* __restrict__ outp,
                                            const unsigned long long* __restrict__ stats,
                                            const float* __restrict__ bnw,
                                            const float* __restrict__ bnb,
                                            float* __restrict__ out) {
  int i = blockIdx.x * 256 + threadIdx.x;
  if (i >= NNODE * NATT) return;
  int colc = i % NATT;
  float x = outp[i];
  float r;
  if (colc < NS) {
    float mean = (float)((double)(long long)stats[colc] * (FXSI / NNODE));
    float ex2  = (float)((double)(long long)stats[NS + colc] * (FXQI / NNODE));
    float var  = ex2 - mean * mean;
    r = (x - mean) * rsqrtf(var + EPSV) * bnw[colc] + bnb[colc];
  } else {
    int u = (colc - NS) / 3;
    float vn = (float)((double)(long long)stats[96 + u] * (FXQI / (3.0 * NNODE)));
    r = x * rsqrtf(vn + EPSV) * bnw[NS + u];
  }
  out[i] = r;
}

extern "C" void kernel_launch(void* const* d_in, const int* in_sizes, int n_in,
                              void* d_out, int out_size, void* d_ws, size_t ws_size,
                              hipStream_t stream) {
  const float* node_attr = (const float*)d_in[0];
  const int*   eidx      = (const int*)d_in[1];
  const float* edge_attr = (const float*)d_in[2];
  const float* esh       = (const float*)d_in[3];
  const float* fw1       = (const float*)d_in[4];
  const float* fb1       = (const float*)d_in[5];
  const float* fw2       = (const float*)d_in[6];
  const float* fb2       = (const float*)d_in[7];
  const float* bnw       = (const float*)d_in[8];
  const float* bnb       = (const float*)d_in[9];
  float* out = (float*)d_out;

  char* ws = (char*)d_ws;
  // layout (bytes) -- total 20,050,752:
  //   Bt2      @ 0        : CPAD2*128*2 =    958,464   (dead after k_tp)
  //   hbf      @ 958464   : EPAD*128*2  = 12,812,288   (dead after k_tp)
  //   summed   @ 13770752 : N*78*8     =   6,240,000   (i64 Q31)
  //   cnt      @ 20010752 : N*4        =      40,000   (u32)
  //   outp     @ 0        : N*78*4     =   3,120,000   (reuses dead head, after k_tp)
  //   partials @ 3120000  : 256*128*8  =     262,144   (inside dead region)
  //   stats    @ 3382144  : 128*8      =       1,024   (inside dead region)
  unsigned short*     Bt2      = (unsigned short*)(ws + 0);
  unsigned short*     hbf      = (unsigned short*)(ws + 958464);
  unsigned long long* summed   = (unsigned long long*)(ws + 13770752);
  unsigned*           cnt      = (unsigned*)(ws + 20010752);
  float*              outp     = (float*)(ws + 0);
  unsigned long long* partials = (unsigned long long*)(ws + 3120000);
  unsigned long long* stats    = (unsigned long long*)(ws + 3382144);

  // single front kernel: Bt2 prep + fc1 MFMA + summed/cnt zero (no memset launch)
  k_front<<<PREP_BLKS + FC1_BLKS + ZERO_BLKS, 256, 0, stream>>>(
      fw2, Bt2, edge_attr, fw1, fb1, hbf, ws + 13770752);
  k_tp<<<EPAD / 64, 256, 0, stream>>>(hbf, Bt2, fb2, eidx, node_attr, esh, summed, cnt);
  k_node<<<NBLK_NODE, 256, 0, stream>>>(summed, cnt, node_attr, outp, partials);
  k_stats<<<1, 128, 0, stream>>>(partials, stats);
  int nelem_blocks = (NNODE * NATT + 255) / 256;
  k_bn<<<nelem_blocks, 256, 0, stream>>>(outp, stats, bnw, bnb, out);
}

// Round 13
// 270.487 us; speedup vs baseline: 1.4105x; 1.0862x over previous
//
#include <hip/hip_runtime.h>
#include <hip/hip_bf16.h>

#define NS 48
#define NV 10
#define NATT 78
#define HID 128
#define WTOT 3364
#define NEDGE 50000
#define NNODE 10000
#define EPAD 50048       // 391 * 128
#define EPSV 1e-5f
#define INV_SQRT3 0.57735026918962576f
#define NORM0 0.13130643285972254f   // 1/sqrt(58)
#define NORM1 0.13130643285972254f

// Fixed-point scales for deterministic integer accumulation
#define FXS  2147483648.0f           // 2^31
#define FXSI (1.0 / 2147483648.0)
#define FXQ  268435456.0f            // 2^28
#define FXQI (1.0 / 268435456.0)

// Repacked Bt2 column layout (tiles of 16 cols; 232 real + 2 pad = 234 tiles)
#define CPAD2 3744
#define NTILE 232
#define NGRP  78          // 78 groups x 3 tiles

#define NBLK_NODE 256     // k_node grid; partials rows

// merged front kernel grid segments
#define PREP_BLKS 1872    // CPAD2*128/256
#define FC1_BLKS  782     // EPAD/64
#define ZERO_BYTES 6280000        // summed (6,240,000) + cnt (40,000)
#define ZERO_BLKS 1534

#define TP_BLKS 391       // EPAD/128 -- single residency round (<= 2/CU * 256)

using half8 = __attribute__((ext_vector_type(8))) _Float16;
using f32x4 = __attribute__((ext_vector_type(4))) float;

__device__ __forceinline__ unsigned short f2h(float x) {
  union { _Float16 h; unsigned short u; } v;
  v.h = (_Float16)x;
  return v.u;
}

__device__ __forceinline__ void atomFx(unsigned long long* p, float x) {
  long long q = (long long)rintf(x * FXS);
  atomicAdd(p, (unsigned long long)q);
}

// cp (repacked col) -> source col in fc_w2/fc_b2, or -1 for zero-pad
__device__ __forceinline__ int cp_to_src(int cp) {
  if (cp < 2304) return cp;                                         // w1
  if (cp < 2784) return 2884 + (cp - 2304);                         // w4
  if (cp < 3552) { int t = cp - 2784; int u = t >> 4, v = t & 15;
                   return (v < 10) ? (2304 + u * 10 + v) : -1; }    // w2
  if (cp < 3712) { int t = cp - 3552; int u = t >> 4, v = t & 15;
                   return (v < 10) ? (2784 + u * 10 + v) : -1; }    // w3
  return -1;                                                        // pad tiles
}

// ---------------- K0: merged {Bt2 prep | fc1 MFMA | workspace zero} -------------
__global__ __launch_bounds__(256) void k_front(const float* __restrict__ w2,
                                               unsigned short* __restrict__ Bt2,
                                               const float* __restrict__ ea,
                                               const float* __restrict__ w1,
                                               const float* __restrict__ b1,
                                               unsigned short* __restrict__ hbf,
                                               char* __restrict__ zbase) {
  __shared__ _Float16 w1T[128][136];   // transposed w1, 16B-aligned rows
  const int bid = blockIdx.x;
  const int tid = threadIdx.x;

  if (bid < PREP_BLKS) {
    int idx = bid * 256 + tid;         // CPAD2*128 total
    int cp = idx >> 7, k = idx & 127;
    int c_src = cp_to_src(cp);
    Bt2[idx] = (c_src >= 0) ? f2h(w2[(size_t)k * WTOT + c_src]) : (unsigned short)0;
    return;
  }
  if (bid >= PREP_BLKS + FC1_BLKS) {
    size_t off = ((size_t)(bid - PREP_BLKS - FC1_BLKS) * 256 + tid) * 16;
    if (off < ZERO_BYTES) *(uint4*)(zbase + off) = make_uint4(0, 0, 0, 0);
    return;
  }

  // ---- fc1 MFMA segment ----
  const int b  = bid - PREP_BLKS;
  const int e0 = b * 64;
  for (int i = tid; i < 128 * 128; i += 256) {
    int k = i >> 7, n = i & 127;       // coalesced read of w1[k][n]
    w1T[n][k] = (_Float16)w1[i];
  }
  __syncthreads();

  const int lane = tid & 63, wid = tid >> 6;
  const int col = lane & 15, quad = lane >> 4;
  int e  = e0 + wid * 16 + col;
  int er = (e < NEDGE) ? e : 0;        // clamp: tail rows discarded downstream
  const float* ear = ea + (size_t)er * 128;
  half8 aF[4];
  #pragma unroll
  for (int ks = 0; ks < 4; ++ks) {
    float4 x0 = *(const float4*)&ear[ks * 32 + quad * 8];
    float4 x1 = *(const float4*)&ear[ks * 32 + quad * 8 + 4];
    half8 a;
    a[0] = (_Float16)x0.x; a[1] = (_Float16)x0.y; a[2] = (_Float16)x0.z; a[3] = (_Float16)x0.w;
    a[4] = (_Float16)x1.x; a[5] = (_Float16)x1.y; a[6] = (_Float16)x1.z; a[7] = (_Float16)x1.w;
    aF[ks] = a;
  }
  const int erow = e0 + wid * 16 + quad * 4;
  #pragma unroll
  for (int t = 0; t < 8; ++t) {
    float b1c = b1[t * 16 + col];
    f32x4 m = {0.f, 0.f, 0.f, 0.f};
    #pragma unroll
    for (int ks = 0; ks < 4; ++ks) {
      half8 bf = *(const half8*)&w1T[t * 16 + col][ks * 32 + quad * 8];
      m = __builtin_amdgcn_mfma_f32_16x16x32_f16(aF[ks], bf, m, 0, 0, 0);
    }
    #pragma unroll
    for (int r = 0; r < 4; ++r) {
      float h = fmaxf(m[r] + b1c, 0.f);
      hbf[(size_t)(erow + r) * 128 + t * 16 + col] = f2h(h);
    }
  }
}

// ---------------- K3: fused GEMM + tensor product -------------------------------
// 8 waves/block, 128 edges/block -> 391 blocks: fits ONE residency round
// (2 blocks/CU x 256 CU = 512 slots), eliminating the 14-block second-round
// tail that made the 782-block version cost ~2x T_block.
// Protocol identical to the proven r8 kernel: waves 0-3 stage via
// global_load_lds; drain-all vmcnt(0) fused with s_barrier; named scalars only.
__global__ __launch_bounds__(512, 4) void k_tp(const unsigned short* __restrict__ hbf,
                                               const unsigned short* __restrict__ Bt2,
                                               const float* __restrict__ fb2,
                                               const int* __restrict__ eidx,
                                               const float* __restrict__ node_attr,
                                               const float* __restrict__ esh,
                                               unsigned long long* __restrict__ summed,
                                               unsigned* __restrict__ cnt) {
  __shared__ half8    bufB[1536];        // 2 groups x 3 tiles x 4KB = 24,576 B
  __shared__ _Float16 sFT[48][128];      // 12,288 B (transposed s, broadcast reads)
  __shared__ _Float16 vFL[128][30];      //  7,680 B
  __shared__ _Float16 b2pH[CPAD2];       //  7,488 B
  // total LDS = 52,032 B -> 2-3 blocks/CU

  const int tid  = threadIdx.x;
  const int wid  = tid >> 6;             // 0..7
  const int lane = tid & 63;
  const int col  = lane & 15;
  const int quad = lane >> 4;
  const int e0   = blockIdx.x * 128;
  const int elb  = wid * 16 + quad * 4;

  // per-lane own-edge scalars (4 rows each); q0 == p0 since NORM0 == NORM1
  float p0v[4];
  float sh1n[4][3];
  int   srcR[4];
  #pragma unroll
  for (int r = 0; r < 4; ++r) {
    int eg = e0 + elb + r;
    bool val = eg < NEDGE;
    srcR[r] = val ? eidx[eg] : -1;
    float sh0 = 0.f, x = 0.f, y = 0.f, z = 0.f;
    if (val) {
      float4 s4 = *(const float4*)&esh[(size_t)eg * 4];
      sh0 = s4.x; x = s4.y; y = s4.z; z = s4.w;
    }
    p0v[r] = sh0 * NORM0;
    sh1n[r][0] = x * NORM1; sh1n[r][1] = y * NORM1; sh1n[r][2] = z * NORM1;
  }
  for (int i = tid; i < CPAD2; i += 512) {
    int c_src = cp_to_src(i);
    b2pH[i] = (c_src >= 0) ? (_Float16)fb2[c_src] : (_Float16)0.f;
  }
  for (int i = tid; i < 128 * NATT; i += 512) {
    int el = i / NATT, a = i % NATT;
    int eg = e0 + el;
    int dst = (eg < NEDGE) ? eidx[NEDGE + eg] : -1;
    float x = (dst >= 0) ? node_attr[(size_t)dst * NATT + a] : 0.f;
    if (a < NS) sFT[a][el] = (_Float16)x; else vFL[el][a - NS] = (_Float16)x;
  }
  __syncthreads();

  // A fragments for this wave's 16 edges (full K=128)
  half8 aF0, aF1, aF2, aF3;
  {
    const half8* hp = (const half8*)hbf;
    size_t arow = (size_t)(e0 + wid * 16 + col) * 16;
    aF0 = hp[arow + 0 * 4 + quad];
    aF1 = hp[arow + 1 * 4 + quad];
    aF2 = hp[arow + 2 * 4 + quad];
    aF3 = hp[arow + 3 * 4 + quad];
  }

  // Staging (waves 0-3 only): dest wave-uniform base + lane*16 (LDS linear by
  // tid within 4KB tile); source pre-swizzled (both-sides rule).
  const char* bt2c = (const char*)Bt2;
  const int colS = (tid >> 4) & 15, k8sS = tid & 15;
  const size_t gOff = (size_t)(colS * 16 + (k8sS ^ colS)) * 16;

  #define STAGE3(G) do {                                                           \
    if (wid < 4) {                                                                 \
      int _t0 = (G) * 3;                                                           \
      char* _db = (char*)bufB + ((G) & 1) * 12288 + wid * 1024;                    \
      _Pragma("unroll")                                                            \
      for (int _t = 0; _t < 3; ++_t)                                               \
        __builtin_amdgcn_global_load_lds(                                          \
          (const __attribute__((address_space(1))) void*)(bt2c + (size_t)(_t0 + _t) * 4096 + gOff), \
          (__attribute__((address_space(3))) void*)(_db + _t * 4096), 16, 0, 0);   \
    }                                                                              \
  } while (0)

  STAGE3(0); STAGE3(1);

  float acc0[4][3] = {};
  float t1a[4] = {};
  float t3a[4][3] = {};

  const int k0 = (0 * 4 + quad) ^ col;
  const int k1 = (1 * 4 + quad) ^ col;
  const int k2 = (2 * 4 + quad) ^ col;
  const int k3 = (3 * 4 + quad) ^ col;
  const int cb = col * 16;

  #pragma unroll 1
  for (int p = 0; p < NGRP; ++p) {
    // drain-all + barrier (fused): staging waves drained their own DMA before
    // the barrier, so after it every wave sees groups p and p+1 in LDS.
    asm volatile("s_waitcnt vmcnt(0)\n\ts_barrier" ::: "memory");

    const int bb = ((p & 1) << 9) + ((p & 1) << 8) + cb;   // (p&1)*768 + col*16
    half8 b00 = bufB[bb +   0 + k0], b01 = bufB[bb +   0 + k1],
          b02 = bufB[bb +   0 + k2], b03 = bufB[bb +   0 + k3];
    half8 b10 = bufB[bb + 256 + k0], b11 = bufB[bb + 256 + k1],
          b12 = bufB[bb + 256 + k2], b13 = bufB[bb + 256 + k3];
    half8 b20 = bufB[bb + 512 + k0], b21 = bufB[bb + 512 + k1],
          b22 = bufB[bb + 512 + k2], b23 = bufB[bb + 512 + k3];

    __builtin_amdgcn_s_setprio(1);
    f32x4 m0 = {0.f, 0.f, 0.f, 0.f};
    f32x4 m1 = {0.f, 0.f, 0.f, 0.f};
    f32x4 m2 = {0.f, 0.f, 0.f, 0.f};
    m0 = __builtin_amdgcn_mfma_f32_16x16x32_f16(aF0, b00, m0, 0, 0, 0);
    m1 = __builtin_amdgcn_mfma_f32_16x16x32_f16(aF0, b10, m1, 0, 0, 0);
    m2 = __builtin_amdgcn_mfma_f32_16x16x32_f16(aF0, b20, m2, 0, 0, 0);
    m0 = __builtin_amdgcn_mfma_f32_16x16x32_f16(aF1, b01, m0, 0, 0, 0);
    m1 = __builtin_amdgcn_mfma_f32_16x16x32_f16(aF1, b11, m1, 0, 0, 0);
    m2 = __builtin_amdgcn_mfma_f32_16x16x32_f16(aF1, b21, m2, 0, 0, 0);
    m0 = __builtin_amdgcn_mfma_f32_16x16x32_f16(aF2, b02, m0, 0, 0, 0);
    m1 = __builtin_amdgcn_mfma_f32_16x16x32_f16(aF2, b12, m1, 0, 0, 0);
    m2 = __builtin_amdgcn_mfma_f32_16x16x32_f16(aF2, b22, m2, 0, 0, 0);
    m0 = __builtin_amdgcn_mfma_f32_16x16x32_f16(aF3, b03, m0, 0, 0, 0);
    m1 = __builtin_amdgcn_mfma_f32_16x16x32_f16(aF3, b13, m1, 0, 0, 0);
    m2 = __builtin_amdgcn_mfma_f32_16x16x32_f16(aF3, b23, m2, 0, 0, 0);
    __builtin_amdgcn_s_setprio(0);

    // all waves done reading buf[p&1] before staging overwrites it
    asm volatile("s_waitcnt lgkmcnt(0)\n\ts_barrier" ::: "memory");
    if (p < NGRP - 2) STAGE3(p + 2);

    // ---- epilogue (named scalars only) ----
    float b2c0 = (float)b2pH[(p * 3 + 0) * 16 + col];
    float b2c1 = (float)b2pH[(p * 3 + 1) * 16 + col];
    float b2c2 = (float)b2pH[(p * 3 + 2) * 16 + col];
    if (p < 48) {                        // region A (w1), u = p
      #pragma unroll
      for (int r = 0; r < 4; ++r) {
        float sfac = (float)sFT[p][elb + r] * p0v[r];
        acc0[r][0] += (m0[r] + b2c0) * sfac;
        acc0[r][1] += (m1[r] + b2c1) * sfac;
        acc0[r][2] += (m2[r] + b2c2) * sfac;
      }
    } else if (p < 58) {                 // region B (w4), u = p-48
      int u3 = (p - 48) * 3;
      #pragma unroll
      for (int r = 0; r < 4; ++r) {
        int el = elb + r;
        float dfac = ((float)vFL[el][u3]     * sh1n[r][0] +
                      (float)vFL[el][u3 + 1] * sh1n[r][1] +
                      (float)vFL[el][u3 + 2] * sh1n[r][2]) * INV_SQRT3;
        acc0[r][0] += (m0[r] + b2c0) * dfac;
        acc0[r][1] += (m1[r] + b2c1) * dfac;
        acc0[r][2] += (m2[r] + b2c2) * dfac;
      }
    } else if (p < 74) {                 // region C (w2), u = 3(p-58)+j
      int u0 = (p - 58) * 3;
      #pragma unroll
      for (int r = 0; r < 4; ++r) {
        int el = elb + r;
        t1a[r] += (m0[r] + b2c0) * (float)sFT[u0][el]
                + (m1[r] + b2c1) * (float)sFT[u0 + 1][el]
                + (m2[r] + b2c2) * (float)sFT[u0 + 2][el];
      }
    } else {                             // region D (w3), T = 3p+j, guard pad
      int ub = (p - 74) * 3;
      int T0 = p * 3;
      #pragma unroll
      for (int r = 0; r < 4; ++r) {
        int el = elb + r;
        {
          float w = m0[r] + b2c0;
          t3a[r][0] += w * (float)vFL[el][(ub + 0) * 3 + 0];
          t3a[r][1] += w * (float)vFL[el][(ub + 0) * 3 + 1];
          t3a[r][2] += w * (float)vFL[el][(ub + 0) * 3 + 2];
        }
        if (T0 + 1 < NTILE) {
          float w = m1[r] + b2c1;
          t3a[r][0] += w * (float)vFL[el][(ub + 1) * 3 + 0];
          t3a[r][1] += w * (float)vFL[el][(ub + 1) * 3 + 1];
          t3a[r][2] += w * (float)vFL[el][(ub + 1) * 3 + 2];
        }
        if (T0 + 2 < NTILE) {
          float w = m2[r] + b2c2;
          t3a[r][0] += w * (float)vFL[el][(ub + 2) * 3 + 0];
          t3a[r][1] += w * (float)vFL[el][(ub + 2) * 3 + 1];
          t3a[r][2] += w * (float)vFL[el][(ub + 2) * 3 + 2];
        }
      }
    }
  }
  #undef STAGE3

  // ---- Flush: registers -> global integer atomics (deterministic) ----
  #pragma unroll
  for (int r = 0; r < 4; ++r) {
    int src = srcR[r];
    if (src < 0) continue;
    unsigned long long* dp = &summed[(size_t)src * NATT];
    #pragma unroll
    for (int j = 0; j < 3; ++j)
      atomFx(dp + j * 16 + col, acc0[r][j]);
    if (col < 10) {
      float q0 = p0v[r];                 // q0 == p0 (NORM0 == NORM1)
      #pragma unroll
      for (int i = 0; i < 3; ++i)
        atomFx(dp + NS + col * 3 + i,
               t1a[r] * sh1n[r][i] + t3a[r][i] * q0);
    }
  }
  if (tid < 128) {
    int eg = e0 + tid;
    if (eg < NEDGE) atomicAdd(&cnt[eidx[eg]], 1u);
  }
}

// ---------------- K4: mean + residual + BN-stat partials (grid-stride) ----------
__global__ __launch_bounds__(256) void k_node(const unsigned long long* __restrict__ summed,
                                              const unsigned* __restrict__ cnt,
                                              const float* __restrict__ node_attr,
                                              float* __restrict__ outp,
                                              unsigned long long* __restrict__ partials) {
  __shared__ unsigned long long ls[NS], lq[NS], lv[NV];
  int tid = threadIdx.x;
  if (tid < NS) { ls[tid] = 0ull; lq[tid] = 0ull; }
  if (tid < NV) lv[tid] = 0ull;
  __syncthreads();
  for (int i = blockIdx.x * 256 + tid; i < NNODE * NATT; i += NBLK_NODE * 256) {
    int row = i / NATT, colc = i % NATT;
    long long sv = (long long)summed[i];
    float sum = (float)((double)sv * FXSI);
    float x = sum / fmaxf((float)cnt[row], 1.f) + node_attr[i];
    outp[i] = x;
    if (colc < NS) {
      atomicAdd(&ls[colc], (unsigned long long)(long long)rintf(x * FXS));
      atomicAdd(&lq[colc], (unsigned long long)(long long)rintf(x * x * FXQ));
    } else {
      atomicAdd(&lv[(colc - NS) / 3], (unsigned long long)(long long)rintf(x * x * FXQ));
    }
  }
  __syncthreads();
  if (tid < 128) {
    unsigned long long v = 0ull;
    if (tid < NS)            v = ls[tid];
    else if (tid < 2 * NS)   v = lq[tid - NS];
    else if (tid < 96 + NV)  v = lv[tid - 96];
    partials[(size_t)blockIdx.x * 128 + tid] = v;
  }
}

// ---------------- K4b: deterministic partial reduction --------------------------
__global__ __launch_bounds__(128) void k_stats(const unsigned long long* __restrict__ partials,
                                               unsigned long long* __restrict__ stats) {
  int c = threadIdx.x;        // 0..127
  unsigned long long s = 0ull;
  for (int b = 0; b < NBLK_NODE; ++b) s += partials[(size_t)b * 128 + c];
  stats[c] = s;
}

// ---------------- K5: batch norm apply ------------------------------------------
__global__ __launch_bounds__(256) void k_bn(const float* __restrict__ outp,
                                            const unsigned long long* __restrict__ stats,
                                            const float* __restrict__ bnw,
                                            const float* __restrict__ bnb,
                                            float* __restrict__ out) {
  int i = blockIdx.x * 256 + threadIdx.x;
  if (i >= NNODE * NATT) return;
  int colc = i % NATT;
  float x = outp[i];
  float r;
  if (colc < NS) {
    float mean = (float)((double)(long long)stats[colc] * (FXSI / NNODE));
    float ex2  = (float)((double)(long long)stats[NS + colc] * (FXQI / NNODE));
    float var  = ex2 - mean * mean;
    r = (x - mean) * rsqrtf(var + EPSV) * bnw[colc] + bnb[colc];
  } else {
    int u = (colc - NS) / 3;
    float vn = (float)((double)(long long)stats[96 + u] * (FXQI / (3.0 * NNODE)));
    r = x * rsqrtf(vn + EPSV) * bnw[NS + u];
  }
  out[i] = r;
}

extern "C" void kernel_launch(void* const* d_in, const int* in_sizes, int n_in,
                              void* d_out, int out_size, void* d_ws, size_t ws_size,
                              hipStream_t stream) {
  const float* node_attr = (const float*)d_in[0];
  const int*   eidx      = (const int*)d_in[1];
  const float* edge_attr = (const float*)d_in[2];
  const float* esh       = (const float*)d_in[3];
  const float* fw1       = (const float*)d_in[4];
  const float* fb1       = (const float*)d_in[5];
  const float* fw2       = (const float*)d_in[6];
  const float* fb2       = (const float*)d_in[7];
  const float* bnw       = (const float*)d_in[8];
  const float* bnb       = (const float*)d_in[9];
  float* out = (float*)d_out;

  char* ws = (char*)d_ws;
  // layout (bytes) -- total 20,050,752:
  //   Bt2      @ 0        : CPAD2*128*2 =    958,464   (dead after k_tp)
  //   hbf      @ 958464   : EPAD*128*2  = 12,812,288   (dead after k_tp)
  //   summed   @ 13770752 : N*78*8     =   6,240,000   (i64 Q31)
  //   cnt      @ 20010752 : N*4        =      40,000   (u32)
  //   outp     @ 0        : N*78*4     =   3,120,000   (reuses dead head, after k_tp)
  //   partials @ 3120000  : 256*128*8  =     262,144   (inside dead region)
  //   stats    @ 3382144  : 128*8      =       1,024   (inside dead region)
  unsigned short*     Bt2      = (unsigned short*)(ws + 0);
  unsigned short*     hbf      = (unsigned short*)(ws + 958464);
  unsigned long long* summed   = (unsigned long long*)(ws + 13770752);
  unsigned*           cnt      = (unsigned*)(ws + 20010752);
  float*              outp     = (float*)(ws + 0);
  unsigned long long* partials = (unsigned long long*)(ws + 3120000);
  unsigned long long* stats    = (unsigned long long*)(ws + 3382144);

  // single front kernel: Bt2 prep + fc1 MFMA + summed/cnt zero
  k_front<<<PREP_BLKS + FC1_BLKS + ZERO_BLKS, 256, 0, stream>>>(
      fw2, Bt2, edge_attr, fw1, fb1, hbf, ws + 13770752);
  k_tp<<<TP_BLKS, 512, 0, stream>>>(hbf, Bt2, fb2, eidx, node_attr, esh, summed, cnt);
  k_node<<<NBLK_NODE, 256, 0, stream>>>(summed, cnt, node_attr, outp, partials);
  k_stats<<<1, 128, 0, stream>>>(partials, stats);
  int nelem_blocks = (NNODE * NATT + 255) / 256;
  k_bn<<<nelem_blocks, 256, 0, stream>>>(outp, stats, bnw, bnb, out);
}